// Round 1
// baseline (968.132 us; speedup 1.0000x reference)
//
#include <hip/hip_runtime.h>
#include <math.h>

// Single-query attention, flash-decode style, fp32.
// B=32, S=4096, D=1024. Memory-bound: K+V = 1.074 GB must stream from HBM.
#define BB 32
#define SS 4096
#define DD 1024
#define CHUNKS 32
#define CHUNK_S (SS / CHUNKS)   // 128 keys per block
#define SCALE 0.03125f          // 1/sqrt(1024)

// Kernel 1: per (b, chunk) partial attention with local softmax.
// block = 256 threads = 4 waves. Wave w handles keys i = w + 4*it.
__global__ __launch_bounds__(256) void attn_partial(
    const float* __restrict__ q,      // [B, D]
    const float* __restrict__ k,      // [B, S, D]
    const float* __restrict__ v,      // [B, S, D]
    const int*   __restrict__ mask,   // [B, S]
    float* __restrict__ part_o,       // [B, CHUNKS, D] (unnormalized)
    float* __restrict__ part_ml)      // [B, CHUNKS, 2] (m, l)
{
    const int c    = blockIdx.x;
    const int b    = blockIdx.y;
    const int tid  = threadIdx.x;
    const int lane = tid & 63;
    const int wave = tid >> 6;   // 0..3

    __shared__ float s_scores[CHUNK_S];
    __shared__ float s_w[CHUNK_S];

    // Q fragment: lane holds float4 at d = 4*lane + 256*j, j=0..3 (16 floats/lane)
    const float* qb = q + (size_t)b * DD;
    float4 qf[4];
#pragma unroll
    for (int j = 0; j < 4; ++j)
        qf[j] = *(const float4*)(qb + 4 * lane + 256 * j);

    const int s0 = c * CHUNK_S;

    // --- Phase 1: scores  (wave-per-key dot product) ---
    for (int it = 0; it < CHUNK_S / 4; ++it) {
        const int i    = wave + 4 * it;       // 0..127 within chunk
        const int srow = s0 + i;
        const float* krow = k + ((size_t)b * SS + srow) * DD;
        float acc = 0.f;
#pragma unroll
        for (int j = 0; j < 4; ++j) {
            float4 kf = *(const float4*)(krow + 4 * lane + 256 * j);
            acc += qf[j].x * kf.x + qf[j].y * kf.y + qf[j].z * kf.z + qf[j].w * kf.w;
        }
        // 64-lane butterfly reduce
#pragma unroll
        for (int off = 32; off > 0; off >>= 1)
            acc += __shfl_xor(acc, off, 64);
        if (lane == 0) {
            float sc = acc * SCALE;
            if (mask[(size_t)b * SS + srow] == 0) sc = -1e30f;
            s_scores[i] = sc;
        }
    }
    __syncthreads();

    // --- Phase 2: local softmax partial (redundant per-thread, LDS broadcast) ---
    float m = -1e30f;
#pragma unroll 8
    for (int i = 0; i < CHUNK_S; ++i) m = fmaxf(m, s_scores[i]);
    if (tid < CHUNK_S) s_w[tid] = expf(s_scores[tid] - m);
    __syncthreads();
    float l = 0.f;
#pragma unroll 8
    for (int i = 0; i < CHUNK_S; ++i) l += s_w[i];

    // --- Phase 3: unnormalized weighted V accumulation ---
    // thread owns d = 4*tid .. 4*tid+3 (256 threads x float4 = 1024 dims)
    const float* vb = v + ((size_t)b * SS + s0) * DD + 4 * tid;
    float4 acc = {0.f, 0.f, 0.f, 0.f};
    for (int i = 0; i < CHUNK_S; ++i) {
        const float w  = s_w[i];
        const float4 vf = *(const float4*)(vb + (size_t)i * DD);
        acc.x += w * vf.x;
        acc.y += w * vf.y;
        acc.z += w * vf.z;
        acc.w += w * vf.w;
    }
    *(float4*)(part_o + ((size_t)b * CHUNKS + c) * DD + 4 * tid) = acc;
    if (tid == 0) {
        part_ml[((size_t)b * CHUNKS + c) * 2 + 0] = m;
        part_ml[((size_t)b * CHUNKS + c) * 2 + 1] = l;
    }
}

// Kernel 2: combine CHUNKS partials per batch row, normalize.
__global__ __launch_bounds__(256) void attn_combine(
    const float* __restrict__ part_o,   // [B, CHUNKS, D]
    const float* __restrict__ part_ml,  // [B, CHUNKS, 2]
    float* __restrict__ out)            // [B, 1, D]
{
    const int b   = blockIdx.x;
    const int tid = threadIdx.x;

    __shared__ float s_m[CHUNKS];
    __shared__ float s_l[CHUNKS];
    __shared__ float s_scale[CHUNKS];

    if (tid < CHUNKS) {
        s_m[tid] = part_ml[((size_t)b * CHUNKS + tid) * 2 + 0];
        s_l[tid] = part_ml[((size_t)b * CHUNKS + tid) * 2 + 1];
    }
    __syncthreads();

    float m = -1e30f;
#pragma unroll
    for (int c = 0; c < CHUNKS; ++c) m = fmaxf(m, s_m[c]);
    if (tid < CHUNKS) s_scale[tid] = expf(s_m[tid] - m);
    __syncthreads();

    float L = 0.f;
#pragma unroll
    for (int c = 0; c < CHUNKS; ++c) L += s_l[c] * s_scale[c];
    const float inv_L = 1.f / L;

    // thread owns d = 4*tid .. 4*tid+3
    float4 acc = {0.f, 0.f, 0.f, 0.f};
    for (int c = 0; c < CHUNKS; ++c) {
        const float sc = s_scale[c];
        const float4 o = *(const float4*)(part_o + ((size_t)b * CHUNKS + c) * DD + 4 * tid);
        acc.x += sc * o.x;
        acc.y += sc * o.y;
        acc.z += sc * o.z;
        acc.w += sc * o.w;
    }
    acc.x *= inv_L; acc.y *= inv_L; acc.z *= inv_L; acc.w *= inv_L;
    *(float4*)(out + (size_t)b * DD + 4 * tid) = acc;
}

extern "C" void kernel_launch(void* const* d_in, const int* in_sizes, int n_in,
                              void* d_out, int out_size, void* d_ws, size_t ws_size,
                              hipStream_t stream) {
    const float* q    = (const float*)d_in[0];
    const float* k    = (const float*)d_in[1];
    const float* v    = (const float*)d_in[2];
    const int*   mask = (const int*)d_in[3];
    float* out = (float*)d_out;

    // workspace layout: part_o [B*CHUNKS*D] floats, then part_ml [B*CHUNKS*2]
    float* part_o  = (float*)d_ws;
    float* part_ml = part_o + (size_t)BB * CHUNKS * DD;

    dim3 grid1(CHUNKS, BB);
    attn_partial<<<grid1, 256, 0, stream>>>(q, k, v, mask, part_o, part_ml);
    attn_combine<<<BB, 256, 0, stream>>>(part_o, part_ml, out);
}